// Round 2
// baseline (4771.702 us; speedup 1.0000x reference)
//
#include <hip/hip_runtime.h>
#include <math.h>

#define N_TOK 65536
#define HID   256
#define NHEAD 8
#define DHEAD 32
#define FFDIM 1024
#define EPS_LN 1e-5f
#define RBLOCKS 512

__device__ __forceinline__ float gelu_f(float x) {
    return 0.5f * x * (1.0f + erff(x * 0.70710678118654752f));
}
__device__ __forceinline__ float bf2f(unsigned short u) {
    return __uint_as_float(((unsigned int)u) << 16);
}
__device__ __forceinline__ unsigned short f2bf(float f) {
    unsigned int x = __float_as_uint(f);
    unsigned int r = ((x >> 16) & 1u) + 0x7fffu;
    return (unsigned short)((x + r) >> 16);
}

// ---------------- per-row mean / rstd (shared by both LN branches) -------------
__global__ __launch_bounds__(256) void stats_kernel(const float* __restrict__ h,
                                                    float* __restrict__ mean,
                                                    float* __restrict__ rstd) {
    const int row = blockIdx.x;
    const int tid = threadIdx.x;
    float x = h[(size_t)row * HID + tid];
    float s = x, s2 = x * x;
    #pragma unroll
    for (int off = 32; off > 0; off >>= 1) {
        s  += __shfl_down(s, off, 64);
        s2 += __shfl_down(s2, off, 64);
    }
    __shared__ float as1[4], as2[4];
    if ((tid & 63) == 0) { as1[tid >> 6] = s; as2[tid >> 6] = s2; }
    __syncthreads();
    if (tid == 0) {
        float S  = as1[0] + as1[1] + as1[2] + as1[3];
        float S2 = as2[0] + as2[1] + as2[2] + as2[3];
        float m = S * (1.0f / HID);
        float v = fmaxf(S2 * (1.0f / HID) - m * m, 0.0f);
        mean[row] = m;
        rstd[row] = rsqrtf(v + EPS_LN);
    }
}

// ---------------- generic tiled GEMM: C = [LN](A) @ W + bias (+res)(+gelu)
// A: [N, K] row-major (fp32 or bf16), W: [K, M] fp32 row-major, C: fp32 or bf16
template<int K, bool LNA, bool GELU_EP, bool RES, bool ABF16, bool CBF16>
__global__ __launch_bounds__(256) void gemm_kernel(
    const void* __restrict__ A, const float* __restrict__ W,
    const float* __restrict__ bias, const float* __restrict__ res,
    const float* __restrict__ lng, const float* __restrict__ lnb,
    const float* __restrict__ mean, const float* __restrict__ rstd,
    void* __restrict__ C, const int M)
{
    __shared__ float As[16][64];   // [k][m]
    __shared__ float Ws[16][64];   // [k][n]
    const int bm = blockIdx.x * 64;
    const int bn = blockIdx.y * 64;
    const int tid = threadIdx.x;
    const int tx = tid & 15, ty = tid >> 4;
    const int lr = tid >> 2;            // A-load row 0..63
    const int lk = (tid & 3) << 2;      // A-load k   0,4,8,12
    const int wk = tid >> 4;            // W-load k   0..15
    const int wn = (tid & 15) << 2;     // W-load n   0..60
    float acc[4][4] = {};
    float mrow = 0.f, rrow = 0.f;
    if (LNA) { mrow = mean[bm + lr]; rrow = rstd[bm + lr]; }
    const float* Af = (const float*)A + (size_t)(bm + lr) * K;
    const unsigned short* Ab = (const unsigned short*)A + (size_t)(bm + lr) * K;
    for (int k0 = 0; k0 < K; k0 += 16) {
        float4 av;
        if (ABF16) {
            const ushort4 u = *(const ushort4*)(Ab + k0 + lk);
            av.x = bf2f(u.x); av.y = bf2f(u.y); av.z = bf2f(u.z); av.w = bf2f(u.w);
        } else {
            av = *(const float4*)(Af + k0 + lk);
        }
        if (LNA) {
            const float4 gv = *(const float4*)(lng + k0 + lk);
            const float4 bv = *(const float4*)(lnb + k0 + lk);
            av.x = (av.x - mrow) * rrow * gv.x + bv.x;
            av.y = (av.y - mrow) * rrow * gv.y + bv.y;
            av.z = (av.z - mrow) * rrow * gv.z + bv.z;
            av.w = (av.w - mrow) * rrow * gv.w + bv.w;
        }
        As[lk + 0][lr] = av.x;
        As[lk + 1][lr] = av.y;
        As[lk + 2][lr] = av.z;
        As[lk + 3][lr] = av.w;
        *(float4*)&Ws[wk][wn] = *(const float4*)(W + (size_t)(k0 + wk) * M + bn + wn);
        __syncthreads();
        #pragma unroll
        for (int kk = 0; kk < 16; ++kk) {
            const float4 a4 = *(const float4*)&As[kk][ty << 2];
            const float4 w4 = *(const float4*)&Ws[kk][tx << 2];
            const float ar[4] = {a4.x, a4.y, a4.z, a4.w};
            const float wr[4] = {w4.x, w4.y, w4.z, w4.w};
            #pragma unroll
            for (int i = 0; i < 4; ++i)
                #pragma unroll
                for (int j = 0; j < 4; ++j)
                    acc[i][j] = fmaf(ar[i], wr[j], acc[i][j]);
        }
        __syncthreads();
    }
    const int orow = bm + (ty << 2);
    const int ocol = bn + (tx << 2);
    const float4 bv = *(const float4*)(bias + ocol);
    #pragma unroll
    for (int i = 0; i < 4; ++i) {
        float4 cv;
        cv.x = acc[i][0] + bv.x;
        cv.y = acc[i][1] + bv.y;
        cv.z = acc[i][2] + bv.z;
        cv.w = acc[i][3] + bv.w;
        if (RES) {
            const float4 rv = *(const float4*)(res + (size_t)(orow + i) * M + ocol);
            cv.x += rv.x; cv.y += rv.y; cv.z += rv.z; cv.w += rv.w;
        }
        if (GELU_EP) {
            cv.x = gelu_f(cv.x); cv.y = gelu_f(cv.y);
            cv.z = gelu_f(cv.z); cv.w = gelu_f(cv.w);
        }
        if (CBF16) {
            ushort4 u;
            u.x = f2bf(cv.x); u.y = f2bf(cv.y); u.z = f2bf(cv.z); u.w = f2bf(cv.w);
            *(ushort4*)((unsigned short*)C + (size_t)(orow + i) * M + ocol) = u;
        } else {
            *(float4*)((float*)C + (size_t)(orow + i) * M + ocol) = cv;
        }
    }
}

// ---------------- stage-1 reduction: per-block partials of
//   kv[c] = sum_n k*v,  ks[c] = sum_n k,  sq = sum q^2, sk = sum k^2
__global__ __launch_bounds__(256) void reduce_kernel(
    const float* __restrict__ q, const float* __restrict__ k,
    const float* __restrict__ v,
    float* __restrict__ pkv, float* __restrict__ pks,
    float* __restrict__ psq, float* __restrict__ psk)
{
    const int b = blockIdx.x;       // 0..RBLOCKS-1
    const int c = threadIdx.x;      // column 0..255, coalesced across threads
    const int rows_per = N_TOK / RBLOCKS;  // 128
    const int r0 = b * rows_per;
    float kv = 0.f, ks = 0.f, sq = 0.f, sk = 0.f;
    for (int r = r0; r < r0 + rows_per; ++r) {
        const size_t idx = (size_t)r * HID + c;
        const float qv = q[idx], kvv = k[idx], vv = v[idx];
        kv = fmaf(kvv, vv, kv);
        ks += kvv;
        sq = fmaf(qv, qv, sq);
        sk = fmaf(kvv, kvv, sk);
    }
    pkv[(size_t)b * HID + c] = kv;
    pks[(size_t)b * HID + c] = ks;
    #pragma unroll
    for (int off = 32; off > 0; off >>= 1) {
        sq += __shfl_down(sq, off, 64);
        sk += __shfl_down(sk, off, 64);
    }
    __shared__ float s1[4], s2[4];
    if ((c & 63) == 0) { s1[c >> 6] = sq; s2[c >> 6] = sk; }
    __syncthreads();
    if (c == 0) {
        psq[b] = s1[0] + s1[1] + s1[2] + s1[3];
        psk[b] = s2[0] + s2[1] + s2[2] + s2[3];
    }
}

// ---------------- stage-2: finalize sums + inv = 1/(|q| * |k|) ----------------
__global__ __launch_bounds__(256) void finalize_kernel(
    const float* __restrict__ pkv, const float* __restrict__ pks,
    const float* __restrict__ psq, const float* __restrict__ psk,
    float* __restrict__ kvsum, float* __restrict__ kssum, float* __restrict__ scal)
{
    const int c = threadIdx.x;
    float kv = 0.f, ks = 0.f;
    for (int b = 0; b < RBLOCKS; ++b) {
        kv += pkv[(size_t)b * HID + c];
        ks += pks[(size_t)b * HID + c];
    }
    kvsum[c] = kv;
    kssum[c] = ks;
    float sq = 0.f, sk = 0.f;
    for (int b = c; b < RBLOCKS; b += 256) { sq += psq[b]; sk += psk[b]; }
    #pragma unroll
    for (int off = 32; off > 0; off >>= 1) {
        sq += __shfl_down(sq, off, 64);
        sk += __shfl_down(sk, off, 64);
    }
    __shared__ float s1[4], s2[4];
    if ((c & 63) == 0) { s1[c >> 6] = sq; s2[c >> 6] = sk; }
    __syncthreads();
    if (c == 0) {
        const float SQ = s1[0] + s1[1] + s1[2] + s1[3];
        const float SK = s2[0] + s2[1] + s2[2] + s2[3];
        scal[0] = rsqrtf(SQ * SK);   // 1/(|q|_F * |k|_F)
    }
}

// ---------------- attention elementwise (in-place over q is safe) -------------
// attn[n,h,d] = (q*kv[h,d]*inv + v*N) / (sum_d q*ks[h,d]*inv + N)
__global__ __launch_bounds__(256) void attn_kernel(
    const float* __restrict__ q, const float* __restrict__ v,
    const float* __restrict__ kvsum, const float* __restrict__ kssum,
    const float* __restrict__ scal, float* __restrict__ attn)
{
    const int gid  = blockIdx.x * 8 + (threadIdx.x >> 5);  // (n,h) group
    const int lane = threadIdx.x & 31;                      // d
    const int n  = gid >> 3;
    const int hh = gid & 7;
    const int col = (hh << 5) + lane;
    const size_t idx = (size_t)n * HID + col;
    const float inv = scal[0];
    const float qv = q[idx];
    float dot = qv * kssum[col];
    #pragma unroll
    for (int off = 16; off > 0; off >>= 1) dot += __shfl_xor(dot, off, 32);
    const float denom = fmaf(dot, inv, (float)N_TOK);
    const float num   = fmaf(qv * kvsum[col], inv, v[idx] * (float)N_TOK);
    attn[idx] = num / denom;
}

extern "C" void kernel_launch(void* const* d_in, const int* in_sizes, int n_in,
                              void* d_out, int out_size, void* d_ws, size_t ws_size,
                              hipStream_t stream) {
    const float* x    = (const float*)d_in[0];
    const float* Wq   = (const float*)d_in[1];
    const float* bq   = (const float*)d_in[2];
    const float* Wk   = (const float*)d_in[3];
    const float* bk   = (const float*)d_in[4];
    const float* Wv   = (const float*)d_in[5];
    const float* bv   = (const float*)d_in[6];
    const float* Wh   = (const float*)d_in[7];
    const float* bh   = (const float*)d_in[8];
    const float* g1kv = (const float*)d_in[9];
    const float* b1kv = (const float*)d_in[10];
    const float* g1q  = (const float*)d_in[11];
    const float* b1q  = (const float*)d_in[12];
    const float* Wf1  = (const float*)d_in[13];
    const float* bf1  = (const float*)d_in[14];
    const float* Wf2  = (const float*)d_in[15];
    const float* bf2  = (const float*)d_in[16];
    const float* g2   = (const float*)d_in[17];
    const float* b2   = (const float*)d_in[18];
    float* out = (float*)d_out;

    // ---- compact workspace with liveness overlap (~194 MB total) ----
    // region R (128 MB): q [64MB fp32] | v [64MB fp32]; later reused as
    //                    act (bf16, 128 MB) once q,v are dead.
    // region S (64 MB):  k (fp32); later reused as hpre once k is dead.
    char* p = (char*)d_ws;
    const size_t nh = (size_t)N_TOK * HID;
    float* q    = (float*)p;
    float* vbuf = (float*)(p + nh * sizeof(float));
    unsigned short* act = (unsigned short*)p;        // overlays q,v
    p += 2 * nh * sizeof(float);
    float* kbuf = (float*)p;
    float* hpre = kbuf;                              // overlays k
    p += nh * sizeof(float);
    float* pkv   = (float*)p; p += (size_t)RBLOCKS * HID * sizeof(float);
    float* pks   = (float*)p; p += (size_t)RBLOCKS * HID * sizeof(float);
    float* psq   = (float*)p; p += RBLOCKS * sizeof(float);
    float* psk   = (float*)p; p += RBLOCKS * sizeof(float);
    float* meanb = (float*)p; p += N_TOK * sizeof(float);
    float* rstdb = (float*)p; p += N_TOK * sizeof(float);
    float* kvs   = (float*)p; p += HID * sizeof(float);
    float* kss   = (float*)p; p += HID * sizeof(float);
    float* scal  = (float*)p; p += 256;

    const dim3 g4(N_TOK / 64, HID / 64);
    const dim3 g16(N_TOK / 64, FFDIM / 64);

    for (int l = 0; l < 3; ++l) {
        const float* hin = (l == 0) ? x : out;
        float* hout = out;   // safe: hin dead before ffn2 writes hout
        const size_t wOff  = (size_t)l * HID * HID;
        const size_t vOff  = (size_t)l * HID;
        const size_t f1Off = (size_t)l * HID * FFDIM;
        const size_t fbOff = (size_t)l * FFDIM;

        stats_kernel<<<N_TOK, 256, 0, stream>>>(hin, meanb, rstdb);
        gemm_kernel<256, true, false, false, false, false><<<g4, 256, 0, stream>>>(
            hin, Wq + wOff, bq + vOff, nullptr, g1q + vOff, b1q + vOff, meanb, rstdb, q, HID);
        gemm_kernel<256, true, false, false, false, false><<<g4, 256, 0, stream>>>(
            hin, Wk + wOff, bk + vOff, nullptr, g1kv + vOff, b1kv + vOff, meanb, rstdb, kbuf, HID);
        gemm_kernel<256, true, false, false, false, false><<<g4, 256, 0, stream>>>(
            hin, Wv + wOff, bv + vOff, nullptr, g1kv + vOff, b1kv + vOff, meanb, rstdb, vbuf, HID);
        reduce_kernel<<<RBLOCKS, 256, 0, stream>>>(q, kbuf, vbuf, pkv, pks, psq, psk);
        finalize_kernel<<<1, 256, 0, stream>>>(pkv, pks, psq, psk, kvs, kss, scal);
        // attn writes into q (in-place); k is dead from here on
        attn_kernel<<<N_TOK * NHEAD / 8, 256, 0, stream>>>(q, vbuf, kvs, kss, scal, q);
        // hpre (aliases kbuf) = attn @ Wh + bh + hin ; v dead after this point
        gemm_kernel<256, false, false, true, false, false><<<g4, 256, 0, stream>>>(
            q, Wh + wOff, bh + vOff, hin, nullptr, nullptr, nullptr, nullptr, hpre, HID);
        stats_kernel<<<N_TOK, 256, 0, stream>>>(hpre, meanb, rstdb);
        // act (bf16, overlays q+v region) = GELU(LN(hpre) @ Wf1 + bf1)
        gemm_kernel<256, true, true, false, false, true><<<g16, 256, 0, stream>>>(
            hpre, Wf1 + f1Off, bf1 + fbOff, nullptr, g2 + vOff, b2 + vOff, meanb, rstdb, act, FFDIM);
        // hout = act @ Wf2 + bf2 + hpre
        gemm_kernel<1024, false, false, true, true, false><<<g4, 256, 0, stream>>>(
            act, Wf2 + f1Off, bf2 + vOff, hpre, nullptr, nullptr, nullptr, nullptr, hout, HID);
    }
}

// Round 4
// 1172.519 us; speedup vs baseline: 4.0696x; 4.0696x over previous
//
#include <hip/hip_runtime.h>
#include <math.h>

#define N_TOK 65536
#define HID   256
#define NHEAD 8
#define FFDIM 1024
#define EPS_LN 1e-5f
#define RBLOCKS 512

typedef __bf16 bf16x8 __attribute__((ext_vector_type(8)));
typedef float  f32x4  __attribute__((ext_vector_type(4)));

__device__ __forceinline__ float gelu_f(float x) {
    return 0.5f * x * (1.0f + erff(x * 0.70710678118654752f));
}
__device__ __forceinline__ float bf2f(unsigned short u) {
    return __uint_as_float(((unsigned int)u) << 16);
}
__device__ __forceinline__ unsigned short f2bf(float f) {
    unsigned int x = __float_as_uint(f);
    unsigned int r = ((x >> 16) & 1u) + 0x7fffu;
    return (unsigned short)((x + r) >> 16);
}

// ---------------- weight fp32 [L,K,M] -> bf16 transposed [L,M,K] --------------
__global__ __launch_bounds__(256) void wconv(
    const float* __restrict__ src, unsigned short* __restrict__ dst,
    const int K, const int M)
{
    const size_t lo = (size_t)blockIdx.z * K * M;
    __shared__ float t[32][33];
    const int r  = threadIdx.x >> 3;
    const int c0 = (threadIdx.x & 7) * 4;
    const int bk = blockIdx.x * 32;
    const int bm = blockIdx.y * 32;
    const float4 v4 = *(const float4*)(src + lo + (size_t)(bk + r) * M + bm + c0);
    t[r][c0] = v4.x; t[r][c0+1] = v4.y; t[r][c0+2] = v4.z; t[r][c0+3] = v4.w;
    __syncthreads();
    ushort4 o;
    o.x = f2bf(t[c0+0][r]);
    o.y = f2bf(t[c0+1][r]);
    o.z = f2bf(t[c0+2][r]);
    o.w = f2bf(t[c0+3][r]);
    *(ushort4*)(dst + lo + (size_t)(bm + r) * K + bk + c0) = o;
}

// ---------------- fused LN stats + normalize -> two bf16 outputs --------------
__global__ __launch_bounds__(256) void ln_dual(
    const float* __restrict__ h,
    const float* __restrict__ gq, const float* __restrict__ bq,
    const float* __restrict__ gkv, const float* __restrict__ bkv,
    unsigned short* __restrict__ lnq, unsigned short* __restrict__ lnkv)
{
    const int row  = blockIdx.x * 4 + (threadIdx.x >> 6);
    const int lane = threadIdx.x & 63;
    const size_t base = (size_t)row * HID + lane * 4;
    const float4 xv = *(const float4*)(h + base);
    float s  = xv.x + xv.y + xv.z + xv.w;
    float s2 = fmaf(xv.x, xv.x, fmaf(xv.y, xv.y, fmaf(xv.z, xv.z, xv.w * xv.w)));
    #pragma unroll
    for (int off = 32; off > 0; off >>= 1) {
        s  += __shfl_xor(s, off, 64);
        s2 += __shfl_xor(s2, off, 64);
    }
    const float m   = s * (1.0f / HID);
    const float var = fmaxf(s2 * (1.0f / HID) - m * m, 0.f);
    const float rs  = rsqrtf(var + EPS_LN);
    const float n0 = (xv.x - m) * rs, n1 = (xv.y - m) * rs;
    const float n2 = (xv.z - m) * rs, n3 = (xv.w - m) * rs;
    const int c = lane * 4;
    float4 g4 = *(const float4*)(gq + c);
    float4 b4 = *(const float4*)(bq + c);
    ushort4 o;
    o.x = f2bf(fmaf(n0, g4.x, b4.x));
    o.y = f2bf(fmaf(n1, g4.y, b4.y));
    o.z = f2bf(fmaf(n2, g4.z, b4.z));
    o.w = f2bf(fmaf(n3, g4.w, b4.w));
    *(ushort4*)(lnq + base) = o;
    g4 = *(const float4*)(gkv + c);
    b4 = *(const float4*)(bkv + c);
    o.x = f2bf(fmaf(n0, g4.x, b4.x));
    o.y = f2bf(fmaf(n1, g4.y, b4.y));
    o.z = f2bf(fmaf(n2, g4.z, b4.z));
    o.w = f2bf(fmaf(n3, g4.w, b4.w));
    *(ushort4*)(lnkv + base) = o;
}

__global__ __launch_bounds__(256) void ln_single(
    const float* __restrict__ h,
    const float* __restrict__ g, const float* __restrict__ b,
    unsigned short* __restrict__ lno)
{
    const int row  = blockIdx.x * 4 + (threadIdx.x >> 6);
    const int lane = threadIdx.x & 63;
    const size_t base = (size_t)row * HID + lane * 4;
    const float4 xv = *(const float4*)(h + base);
    float s  = xv.x + xv.y + xv.z + xv.w;
    float s2 = fmaf(xv.x, xv.x, fmaf(xv.y, xv.y, fmaf(xv.z, xv.z, xv.w * xv.w)));
    #pragma unroll
    for (int off = 32; off > 0; off >>= 1) {
        s  += __shfl_xor(s, off, 64);
        s2 += __shfl_xor(s2, off, 64);
    }
    const float m   = s * (1.0f / HID);
    const float var = fmaxf(s2 * (1.0f / HID) - m * m, 0.f);
    const float rs  = rsqrtf(var + EPS_LN);
    const int c = lane * 4;
    const float4 g4 = *(const float4*)(g + c);
    const float4 b4 = *(const float4*)(b + c);
    ushort4 o;
    o.x = f2bf(fmaf((xv.x - m) * rs, g4.x, b4.x));
    o.y = f2bf(fmaf((xv.y - m) * rs, g4.y, b4.y));
    o.z = f2bf(fmaf((xv.z - m) * rs, g4.z, b4.z));
    o.w = f2bf(fmaf((xv.w - m) * rs, g4.w, b4.w));
    *(ushort4*)(lno + base) = o;
}

// ---------------- bf16 MFMA GEMM: C = A[N,K] @ Wt[M,K]^T + bias (+res)(+gelu)
// 128x128 tile, BK=32, 4 waves (2x2), 4x4 16x16x32 fragments per wave.
template<int K, bool GELU_EP, bool RES, bool CBF16>
__global__ __launch_bounds__(256, 2) void mfma_gemm(
    const unsigned short* __restrict__ A,
    const unsigned short* __restrict__ Wt,
    const float* __restrict__ bias,
    const float* __restrict__ res,
    void* __restrict__ C, const int M)
{
    constexpr int KT  = K / 32;
    constexpr int LDT = 40;             // 32 + 8 pad (80 B rows, 16B-aligned)
    __shared__ __align__(16) unsigned short Abuf[2][128 * LDT];
    __shared__ __align__(16) unsigned short Bbuf[2][128 * LDT];
    const int tid = threadIdx.x;
    const int bm = blockIdx.x * 128;
    const int bn = blockIdx.y * 128;
    const int srow = tid >> 2;
    const int sko  = tid & 3;
    const unsigned short* Ag = A  + (size_t)(bm + srow) * K + sko * 8;
    const unsigned short* Bg = Wt + (size_t)(bn + srow) * K + sko * 8;
    const int lds_off = srow * LDT + sko * 8;

    const int lane = tid & 63;
    const int wv   = tid >> 6;
    const int wr   = (wv >> 1) * 64;
    const int wc   = (wv & 1) * 64;
    const int lrow = lane & 15;
    const int kgrp = lane >> 4;

    f32x4 acc[4][4];
    #pragma unroll
    for (int i = 0; i < 4; ++i)
        #pragma unroll
        for (int j = 0; j < 4; ++j)
            acc[i][j] = (f32x4){0.f, 0.f, 0.f, 0.f};

    bf16x8 ra0 = *(const bf16x8*)(Ag);
    bf16x8 ra1 = *(const bf16x8*)(Ag + (size_t)64 * K);
    bf16x8 rb0 = *(const bf16x8*)(Bg);
    bf16x8 rb1 = *(const bf16x8*)(Bg + (size_t)64 * K);
    *(bf16x8*)&Abuf[0][lds_off]            = ra0;
    *(bf16x8*)&Abuf[0][lds_off + 64 * LDT] = ra1;
    *(bf16x8*)&Bbuf[0][lds_off]            = rb0;
    *(bf16x8*)&Bbuf[0][lds_off + 64 * LDT] = rb1;
    __syncthreads();

    for (int kt = 0; kt < KT; ++kt) {
        const int cur = kt & 1;
        if (kt + 1 < KT) {
            const int ko = (kt + 1) * 32;
            ra0 = *(const bf16x8*)(Ag + ko);
            ra1 = *(const bf16x8*)(Ag + (size_t)64 * K + ko);
            rb0 = *(const bf16x8*)(Bg + ko);
            rb1 = *(const bf16x8*)(Bg + (size_t)64 * K + ko);
        }
        bf16x8 af[4], bfr[4];
        #pragma unroll
        for (int mi = 0; mi < 4; ++mi)
            af[mi] = *(const bf16x8*)&Abuf[cur][(wr + mi * 16 + lrow) * LDT + kgrp * 8];
        #pragma unroll
        for (int ni = 0; ni < 4; ++ni)
            bfr[ni] = *(const bf16x8*)&Bbuf[cur][(wc + ni * 16 + lrow) * LDT + kgrp * 8];
        #pragma unroll
        for (int mi = 0; mi < 4; ++mi)
            #pragma unroll
            for (int ni = 0; ni < 4; ++ni)
                acc[mi][ni] = __builtin_amdgcn_mfma_f32_16x16x32_bf16(
                    af[mi], bfr[ni], acc[mi][ni], 0, 0, 0);
        if (kt + 1 < KT) {
            __syncthreads();
            const int nxt = cur ^ 1;
            *(bf16x8*)&Abuf[nxt][lds_off]            = ra0;
            *(bf16x8*)&Abuf[nxt][lds_off + 64 * LDT] = ra1;
            *(bf16x8*)&Bbuf[nxt][lds_off]            = rb0;
            *(bf16x8*)&Bbuf[nxt][lds_off + 64 * LDT] = rb1;
            __syncthreads();
        }
    }
    // epilogue: D[row=(lane>>4)*4+r][col=lane&15] per 16x16 fragment
    #pragma unroll
    for (int mi = 0; mi < 4; ++mi) {
        #pragma unroll
        for (int ni = 0; ni < 4; ++ni) {
            const int col = bn + wc + ni * 16 + lrow;
            const float bv = bias[col];
            #pragma unroll
            for (int r = 0; r < 4; ++r) {
                const int row = bm + wr + mi * 16 + kgrp * 4 + r;
                float v = acc[mi][ni][r] + bv;
                if (RES)     v += res[(size_t)row * M + col];
                if (GELU_EP) v  = gelu_f(v);
                if (CBF16) ((unsigned short*)C)[(size_t)row * M + col] = f2bf(v);
                else       ((float*)C)[(size_t)row * M + col] = v;
            }
        }
    }
}

// ---------------- stage-1 reduction over bf16 q/k/v ---------------------------
__global__ __launch_bounds__(256) void reduce_kernel(
    const unsigned short* __restrict__ q, const unsigned short* __restrict__ k,
    const unsigned short* __restrict__ v,
    float* __restrict__ pkv, float* __restrict__ pks,
    float* __restrict__ psq, float* __restrict__ psk)
{
    const int b = blockIdx.x;
    const int c = threadIdx.x;
    const int rows_per = N_TOK / RBLOCKS;
    const int r0 = b * rows_per;
    float kv = 0.f, ks = 0.f, sq = 0.f, sk = 0.f;
    for (int r = r0; r < r0 + rows_per; ++r) {
        const size_t idx = (size_t)r * HID + c;
        const float qv = bf2f(q[idx]);
        const float kvv = bf2f(k[idx]);
        const float vv = bf2f(v[idx]);
        kv = fmaf(kvv, vv, kv);
        ks += kvv;
        sq = fmaf(qv, qv, sq);
        sk = fmaf(kvv, kvv, sk);
    }
    pkv[(size_t)b * HID + c] = kv;
    pks[(size_t)b * HID + c] = ks;
    #pragma unroll
    for (int off = 32; off > 0; off >>= 1) {
        sq += __shfl_down(sq, off, 64);
        sk += __shfl_down(sk, off, 64);
    }
    __shared__ float s1[4], s2[4];
    if ((c & 63) == 0) { s1[c >> 6] = sq; s2[c >> 6] = sk; }
    __syncthreads();
    if (c == 0) {
        psq[b] = s1[0] + s1[1] + s1[2] + s1[3];
        psk[b] = s2[0] + s2[1] + s2[2] + s2[3];
    }
}

// ---------------- stage-2 finalize -------------------------------------------
__global__ __launch_bounds__(256) void finalize_kernel(
    const float* __restrict__ pkv, const float* __restrict__ pks,
    const float* __restrict__ psq, const float* __restrict__ psk,
    float* __restrict__ kvsum, float* __restrict__ kssum, float* __restrict__ scal)
{
    const int c = threadIdx.x;
    float kv = 0.f, ks = 0.f;
    for (int b = 0; b < RBLOCKS; ++b) {
        kv += pkv[(size_t)b * HID + c];
        ks += pks[(size_t)b * HID + c];
    }
    kvsum[c] = kv;
    kssum[c] = ks;
    float sq = 0.f, sk = 0.f;
    for (int b = c; b < RBLOCKS; b += 256) { sq += psq[b]; sk += psk[b]; }
    #pragma unroll
    for (int off = 32; off > 0; off >>= 1) {
        sq += __shfl_down(sq, off, 64);
        sk += __shfl_down(sk, off, 64);
    }
    __shared__ float s1[4], s2[4];
    if ((c & 63) == 0) { s1[c >> 6] = sq; s2[c >> 6] = sk; }
    __syncthreads();
    if (c == 0) {
        const float SQ = s1[0] + s1[1] + s1[2] + s1[3];
        const float SK = s2[0] + s2[1] + s2[2] + s2[3];
        scal[0] = rsqrtf(SQ * SK);
    }
}

// ---------------- attention elementwise, bf16 in / bf16 out (in-place on q) ---
__global__ __launch_bounds__(256) void attn_kernel(
    unsigned short* __restrict__ q, const unsigned short* __restrict__ v,
    const float* __restrict__ kvsum, const float* __restrict__ kssum,
    const float* __restrict__ scal)
{
    const int gid  = blockIdx.x * 8 + (threadIdx.x >> 5);
    const int lane = threadIdx.x & 31;
    const int n  = gid >> 3;
    const int hh = gid & 7;
    const int col = (hh << 5) + lane;
    const size_t idx = (size_t)n * HID + col;
    const float inv = scal[0];
    const float qv = bf2f(q[idx]);
    float dot = qv * kssum[col];
    #pragma unroll
    for (int off = 16; off > 0; off >>= 1) dot += __shfl_xor(dot, off, 32);
    const float denom = fmaf(dot, inv, (float)N_TOK);
    const float num   = fmaf(qv * kvsum[col], inv, bf2f(v[idx]) * (float)N_TOK);
    q[idx] = f2bf(num / denom);
}

extern "C" void kernel_launch(void* const* d_in, const int* in_sizes, int n_in,
                              void* d_out, int out_size, void* d_ws, size_t ws_size,
                              hipStream_t stream) {
    const float* x    = (const float*)d_in[0];
    const float* Wq   = (const float*)d_in[1];
    const float* bq   = (const float*)d_in[2];
    const float* Wk   = (const float*)d_in[3];
    const float* bk   = (const float*)d_in[4];
    const float* Wv   = (const float*)d_in[5];
    const float* bv   = (const float*)d_in[6];
    const float* Wh   = (const float*)d_in[7];
    const float* bh   = (const float*)d_in[8];
    const float* g1kv = (const float*)d_in[9];
    const float* b1kv = (const float*)d_in[10];
    const float* g1q  = (const float*)d_in[11];
    const float* b1q  = (const float*)d_in[12];
    const float* Wf1  = (const float*)d_in[13];
    const float* bf1  = (const float*)d_in[14];
    const float* Wf2  = (const float*)d_in[15];
    const float* bf2  = (const float*)d_in[16];
    const float* g2   = (const float*)d_in[17];
    const float* b2   = (const float*)d_in[18];
    float* out = (float*)d_out;

    // ---- workspace (~229.6 MiB total; must stay under 256 MiB) ----
    // act region (128 MiB) overlays {lnq, lnkv, qb, kb} (all dead by FFN1).
    // lnh overlays vb (dead after attn). attn writes in-place over qb.
    char* p = (char*)d_ws;
    const size_t nh = (size_t)N_TOK * HID;            // 16M elems
    unsigned short* lnq  = (unsigned short*)p;                 // 32 MiB
    unsigned short* lnkv = (unsigned short*)(p + nh * 2);      // 32 MiB
    unsigned short* qb   = (unsigned short*)(p + nh * 4);      // 32 MiB
    unsigned short* kb   = (unsigned short*)(p + nh * 6);      // 32 MiB
    unsigned short* act  = (unsigned short*)p;                 // 128 MiB overlay
    p += nh * 8;
    unsigned short* vb  = (unsigned short*)p;                  // 32 MiB
    unsigned short* lnh = vb;                                  // overlay
    p += nh * 2;
    float* hpre = (float*)p; p += nh * 4;                      // 64 MiB
    unsigned short* wtq  = (unsigned short*)p; p += (size_t)3 * HID * HID * 2;
    unsigned short* wtk  = (unsigned short*)p; p += (size_t)3 * HID * HID * 2;
    unsigned short* wtv  = (unsigned short*)p; p += (size_t)3 * HID * HID * 2;
    unsigned short* wth  = (unsigned short*)p; p += (size_t)3 * HID * HID * 2;
    unsigned short* wtf1 = (unsigned short*)p; p += (size_t)3 * HID * FFDIM * 2;
    unsigned short* wtf2 = (unsigned short*)p; p += (size_t)3 * FFDIM * HID * 2;
    float* pkv   = (float*)p; p += (size_t)RBLOCKS * HID * sizeof(float);
    float* pks   = (float*)p; p += (size_t)RBLOCKS * HID * sizeof(float);
    float* psq   = (float*)p; p += RBLOCKS * sizeof(float);
    float* psk   = (float*)p; p += RBLOCKS * sizeof(float);
    float* kvs   = (float*)p; p += HID * sizeof(float);
    float* kss   = (float*)p; p += HID * sizeof(float);
    float* scal  = (float*)p; p += 256;

    // ---- weights -> bf16 transposed [M][K], all 3 layers ----
    wconv<<<dim3(8, 8, 3),  256, 0, stream>>>(Wq,  wtq,  HID,  HID);
    wconv<<<dim3(8, 8, 3),  256, 0, stream>>>(Wk,  wtk,  HID,  HID);
    wconv<<<dim3(8, 8, 3),  256, 0, stream>>>(Wv,  wtv,  HID,  HID);
    wconv<<<dim3(8, 8, 3),  256, 0, stream>>>(Wh,  wth,  HID,  HID);
    wconv<<<dim3(8, 32, 3), 256, 0, stream>>>(Wf1, wtf1, HID,  FFDIM);
    wconv<<<dim3(32, 8, 3), 256, 0, stream>>>(Wf2, wtf2, FFDIM, HID);

    const dim3 gQ(N_TOK / 128, HID / 128);    // (512, 2)
    const dim3 gF(N_TOK / 128, FFDIM / 128);  // (512, 8)

    for (int l = 0; l < 3; ++l) {
        const float* hin = (l == 0) ? x : out;
        const size_t vOff  = (size_t)l * HID;
        const size_t fbOff = (size_t)l * FFDIM;
        const size_t wO    = (size_t)l * HID * HID;
        const size_t fO    = (size_t)l * HID * FFDIM;

        ln_dual<<<N_TOK / 4, 256, 0, stream>>>(
            hin, g1q + vOff, b1q + vOff, g1kv + vOff, b1kv + vOff, lnq, lnkv);
        mfma_gemm<HID, false, false, true><<<gQ, 256, 0, stream>>>(
            lnq,  wtq + wO, bq + vOff, nullptr, qb, HID);
        mfma_gemm<HID, false, false, true><<<gQ, 256, 0, stream>>>(
            lnkv, wtk + wO, bk + vOff, nullptr, kb, HID);
        mfma_gemm<HID, false, false, true><<<gQ, 256, 0, stream>>>(
            lnkv, wtv + wO, bv + vOff, nullptr, vb, HID);
        reduce_kernel<<<RBLOCKS, 256, 0, stream>>>(qb, kb, vb, pkv, pks, psq, psk);
        finalize_kernel<<<1, 256, 0, stream>>>(pkv, pks, psq, psk, kvs, kss, scal);
        attn_kernel<<<N_TOK, 256, 0, stream>>>(qb, vb, kvs, kss, scal);
        mfma_gemm<HID, false, true, false><<<gQ, 256, 0, stream>>>(
            qb, wth + wO, bh + vOff, hin, hpre, HID);
        ln_single<<<N_TOK / 4, 256, 0, stream>>>(hpre, g2 + vOff, b2 + vOff, lnh);
        mfma_gemm<HID, true, false, true><<<gF, 256, 0, stream>>>(
            lnh, wtf1 + fO, bf1 + fbOff, nullptr, act, FFDIM);
        mfma_gemm<FFDIM, false, true, false><<<gQ, 256, 0, stream>>>(
            act, wtf2 + fO, bf2 + vOff, hpre, out, HID);
    }
}